// Round 11
// baseline (1716.876 us; speedup 1.0000x reference)
//
#include <hip/hip_runtime.h>

#define BATCH 8
#define NPTS 4096
#define DIM 64
#define KNN 20
#define BI 32            // i-rows per block
#define CJ 128           // j-chunk
#define MCAND 24         // top-M margin (M > K)
#define NTHREADS 256
#define NCHUNK (NPTS / CJ)
#define RMP 68           // row-major xi pitch (conflict-free float4)

typedef unsigned long long ull;

// numpy np.sum(row of 64 squares) semantics (source-derived):
//   reduce init = copy first element (skip_first_count=1); inner loop adds
//   pairwise_sum(a+1, 63): r[l] = a[1+l]; 6 strided passes (a[9..56]);
//   tree ((r0+r1)+(r2+r3))+((r4+r5)+(r6+r7)); sequential tail a[57..63];
//   finally a[0] + res.
__device__ __forceinline__ float np_sumsq64(const float* __restrict__ xv) {
#pragma clang fp contract(off)
    float r[8];
#pragma unroll
    for (int l = 0; l < 8; ++l) { float v = xv[1 + l]; r[l] = v * v; }
#pragma unroll
    for (int t = 1; t < 7; ++t)
#pragma unroll
        for (int l = 0; l < 8; ++l) {
            float v = xv[1 + 8 * t + l];
            float p = v * v;
            r[l] = r[l] + p;
        }
    float res = ((r[0] + r[1]) + (r[2] + r[3])) + ((r[4] + r[5]) + (r[6] + r[7]));
#pragma unroll
    for (int d = 57; d < 64; ++d) { float v = xv[d]; float p = v * v; res = res + p; }
    float a0 = xv[0] * xv[0];
    return a0 + res;
}

// BLAS sgemm semantics (np.einsum optimize=True / matmul translation):
// single accumulator per output element, k ascending, FMA, acc starts at 0.
__device__ __forceinline__ float np_blas_dot64(const float* __restrict__ xi_,
                                               const float* __restrict__ xj_) {
    float acc = 0.f;
#pragma unroll
    for (int d = 0; d < DIM; ++d) acc = fmaf(xi_[d], xj_[d], acc);
    return acc;
}

__global__ __launch_bounds__(NTHREADS) void edge_knn_kernel(const float* __restrict__ x,
                                                            float* __restrict__ out) {
    __shared__ __align__(16) float sXiT[DIM * BI];     // [d][i] transposed (compute phase)
    __shared__ __align__(16) float sXiRM[BI * RMP];    // [i][d] row-major (rescore/emit)
    __shared__ float sSqni[BI];
    __shared__ float sSqnj[CJ];
    __shared__ int   sFinal[BI][MCAND];
    __shared__ __align__(16) float sU[128 * 65 + 128 * 33];  // xjRM + distT; reused for merge

    float* xjRM  = sU;                 // [CJ][65]
    float* distT = sU + 128 * 65;      // [CJ][33] dist[j][i]
    ull*   mbk   = (ull*)sU;           // [BI][8][MCAND] sorted key lists (49152 B)
    int*   pb    = (int*)((char*)sU + (size_t)BI * 8 * MCAND * 8);  // [BI][8] merge ptrs

    const int tid = threadIdx.x;
    const int blk = blockIdx.x;
    const int b   = blk / (NPTS / BI);
    const int i0  = (blk % (NPTS / BI)) * BI;
    const float* xb = x + (size_t)b * NPTS * DIM;

    // ---- stage central tile: transposed + row-major ----
    for (int idx = tid; idx < BI * (DIM / 4); idx += NTHREADS) {
        int ii = idx >> 4, c = idx & 15;
        float4 v = *(const float4*)(xb + (size_t)(i0 + ii) * DIM + c * 4);
        sXiT[(4 * c + 0) * BI + ii] = v.x;
        sXiT[(4 * c + 1) * BI + ii] = v.y;
        sXiT[(4 * c + 2) * BI + ii] = v.z;
        sXiT[(4 * c + 3) * BI + ii] = v.w;
        *(float4*)&sXiRM[ii * RMP + 4 * c] = v;
    }
    __syncthreads();
    if (tid < BI) {
        float s = 0.f;
        for (int d = 0; d < DIM; ++d) { float v = sXiT[d * BI + tid]; s = fmaf(v, v, s); }
        sSqni[tid] = s;
    }

    // per-thread sorted top-24 list of stage-1 keys
    ull lkey[MCAND];
#pragma unroll
    for (int s = 0; s < MCAND; ++s) lkey[s] = ~0ull;

    const int a  = tid & 7;   // compute role: i-group (i = 4a..4a+3)
    const int bq = tid >> 3;  // compute role: j base (j = bq + 32u)
    const int si = tid >> 3;  // select role: i row
    const int st = tid & 7;   // select role: j sixteenth

    for (int ch = 0; ch < NCHUNK; ++ch) {
        const int j0 = ch * CJ;
        __syncthreads();
        // ---- stage xj chunk (coalesced) ----
        for (int idx = tid; idx < CJ * (DIM / 4); idx += NTHREADS) {
            int r = idx >> 4, c = idx & 15;
            float4 v = *(const float4*)(xb + (size_t)(j0 + r) * DIM + c * 4);
            xjRM[r * 65 + 4 * c + 0] = v.x;
            xjRM[r * 65 + 4 * c + 1] = v.y;
            xjRM[r * 65 + 4 * c + 2] = v.z;
            xjRM[r * 65 + 4 * c + 3] = v.w;
        }
        __syncthreads();
        if (tid < CJ) {
            float s = 0.f;
            for (int d = 0; d < DIM; ++d) { float v = xjRM[tid * 65 + d]; s = fmaf(v, v, s); }
            sSqnj[tid] = s;
        }
        __syncthreads();
        // ---- 4i x 4j inner products (fast proxy; any rounding ok) ----
        float acc[4][4];
#pragma unroll
        for (int u = 0; u < 4; ++u)
#pragma unroll
            for (int q = 0; q < 4; ++q) acc[u][q] = 0.f;
#pragma unroll 8
        for (int d = 0; d < DIM; ++d) {
            float4 xi4 = *(const float4*)&sXiT[d * BI + 4 * a];
            float xj[4];
#pragma unroll
            for (int u = 0; u < 4; ++u) xj[u] = xjRM[(bq + 32 * u) * 65 + d];
#pragma unroll
            for (int u = 0; u < 4; ++u) {
                acc[u][0] = fmaf(xi4.x, xj[u], acc[u][0]);
                acc[u][1] = fmaf(xi4.y, xj[u], acc[u][1]);
                acc[u][2] = fmaf(xi4.z, xj[u], acc[u][2]);
                acc[u][3] = fmaf(xi4.w, xj[u], acc[u][3]);
            }
        }
#pragma unroll
        for (int u = 0; u < 4; ++u) {
            int jl = bq + 32 * u;
#pragma unroll
            for (int q = 0; q < 4; ++q) {
                int il = 4 * a + q;
                distT[jl * 33 + il] = sSqni[il] + sSqnj[jl] - 2.f * acc[u][q];
            }
        }
        __syncthreads();
        // ---- select: each thread scans its 16 j's of its row ----
        for (int s = 0; s < 16; ++s) {
            int jl = st * 16 + s;
            float dv = distT[jl * 33 + si];
            ull key = ((ull)__float_as_uint(dv + 1.0f) << 12) | (ull)(j0 + jl);
            if (key < lkey[MCAND - 1]) {
                ull cur = key;
#pragma unroll
                for (int t = 0; t < MCAND; ++t) {
                    ull lo = cur < lkey[t] ? cur : lkey[t];
                    ull hi = cur < lkey[t] ? lkey[t] : cur;
                    lkey[t] = lo; cur = hi;
                }
            }
        }
    }
    __syncthreads();
    // ---- dump sorted lists (xjRM/distT dead) ----
#pragma unroll
    for (int s = 0; s < MCAND; ++s) mbk[(si * 8 + st) * MCAND + s] = lkey[s];
    __syncthreads();
    // ---- 8-way merge per row -> top-24 candidate indices ----
    if (st == 0) {
        int* p = pb + si * 8;
        for (int t = 0; t < 8; ++t) p[t] = 0;
        for (int slot = 0; slot < MCAND; ++slot) {
            ull best = ~0ull; int bt = 0;
            for (int t = 0; t < 8; ++t) {
                int pt = p[t];
                if (pt < MCAND) {
                    ull v = mbk[(si * 8 + t) * MCAND + pt];
                    if (v < best) { best = v; bt = t; }
                }
            }
            p[bt]++;
            sFinal[si][slot] = (int)(best & 0xFFFull);
        }
    }
    __syncthreads();
    // ---- rescore: EMULATE numpy f32 adjacency bit-exactly ----
    // inner = BLAS sgemm seq-FMA ascending (np_blas_dot64)
    // sq    = np.sum reduce: first-element init + pairwise_sum(63) (np_sumsq64)
    // adj   = fl( fl(sq_i - fl(2*inner)) + sq_j ); order (adj asc, j asc).
    ull kk[3];
    {
        float xi_[DIM];
#pragma unroll
        for (int d4 = 0; d4 < DIM / 4; ++d4) {
            float4 v = *(const float4*)&sXiRM[si * RMP + 4 * d4];
            xi_[4 * d4 + 0] = v.x; xi_[4 * d4 + 1] = v.y;
            xi_[4 * d4 + 2] = v.z; xi_[4 * d4 + 3] = v.w;
        }
        const float sqi32 = np_sumsq64(xi_);
#pragma unroll
        for (int c = 0; c < 3; ++c) {
            const int j = sFinal[si][st * 3 + c];
            const float* pxj = xb + (size_t)j * DIM;
            float xj_[DIM];
#pragma unroll
            for (int d4 = 0; d4 < DIM / 4; ++d4) {
                float4 v = *(const float4*)(pxj + 4 * d4);
                xj_[4 * d4 + 0] = v.x; xj_[4 * d4 + 1] = v.y;
                xj_[4 * d4 + 2] = v.z; xj_[4 * d4 + 3] = v.w;
            }
            const float inn   = np_blas_dot64(xi_, xj_);
            const float sqj32 = np_sumsq64(xj_);
            float adj32;
            {
#pragma clang fp contract(off)
                adj32 = (sqi32 - 2.0f * inn) + sqj32;
            }
            unsigned int bits = __float_as_uint(adj32);
            unsigned int mu = (bits & 0x80000000u) ? ~bits : (bits | 0x80000000u);
            kk[c] = ((ull)mu << 32) | (unsigned int)j;
        }
    }
    // ---- top-20 via 8-lane group selection (emulated order, index tie-break) ----
    for (int k = 0; k < KNN; ++k) {
        ull m = kk[0] < kk[1] ? kk[0] : kk[1];
        m = m < kk[2] ? m : kk[2];
#pragma unroll
        for (int w = 1; w < 8; w <<= 1) {
            ull o = (ull)__shfl_xor((long long)m, w, 8);
            m = o < m ? o : m;
        }
#pragma unroll
        for (int c = 0; c < 3; ++c) if (kk[c] == m) kk[c] = ~0ull;
        if (st == 0) sFinal[si][k] = (int)(m & 0xFFFFFFFFull);
    }
    __syncthreads();
    // ---- fused emit: [i0..i0+31] x 20 x 128, coalesced float4 ----
    const size_t obase = (size_t)(b * NPTS + i0) * (KNN * 2 * DIM);
    for (int v = tid; v < BI * KNN * 2 * DIM / 4; v += NTHREADS) {
        int v4 = v * 4;
        int ii = v4 / (KNN * 2 * DIM);
        int r  = v4 % (KNN * 2 * DIM);
        int k  = r / (2 * DIM);
        int d  = r % (2 * DIM);
        float4 o;
        if (d < DIM) {
            o = *(const float4*)&sXiRM[ii * RMP + d];
        } else {
            int dd = d - DIM;
            int j  = sFinal[ii][k];
            float4 n4 = *(const float4*)(xb + (size_t)j * DIM + dd);
            float4 c4 = *(const float4*)&sXiRM[ii * RMP + dd];
            o.x = n4.x - c4.x;
            o.y = n4.y - c4.y;
            o.z = n4.z - c4.z;
            o.w = n4.w - c4.w;
        }
        *(float4*)(out + obase + v4) = o;
    }
}

extern "C" void kernel_launch(void* const* d_in, const int* in_sizes, int n_in,
                              void* d_out, int out_size, void* d_ws, size_t ws_size,
                              hipStream_t stream) {
    const float* x = (const float*)d_in[0];
    float* out = (float*)d_out;
    dim3 grid(BATCH * (NPTS / BI));
    hipLaunchKernelGGL(edge_knn_kernel, grid, dim3(NTHREADS), 0, stream, x, out);
}

// Round 12
// 931.170 us; speedup vs baseline: 1.8438x; 1.8438x over previous
//
#include <hip/hip_runtime.h>

#define BATCH 8
#define NPTS 4096
#define DIM 64
#define KNN 20
#define BI 32            // i-rows per block
#define CJ 64            // j-chunk
#define MCAND 24
#define NTHREADS 256
#define NCHUNK (NPTS / CJ)   // 64
#define RMP 68           // sXiRM pitch
#define XJP 66           // xjT [d][j] pitch (even -> aligned b64)
#define DTP 66           // distT [i][j] pitch (even -> aligned b64)

typedef unsigned long long ull;
typedef unsigned int u32;

// ===== VALIDATED R11 recipes (bit-exact vs checker) — do not touch =====
__device__ __forceinline__ float np_sumsq64(const float* __restrict__ xv) {
#pragma clang fp contract(off)
    float r[8];
#pragma unroll
    for (int l = 0; l < 8; ++l) { float v = xv[1 + l]; r[l] = v * v; }
#pragma unroll
    for (int t = 1; t < 7; ++t)
#pragma unroll
        for (int l = 0; l < 8; ++l) {
            float v = xv[1 + 8 * t + l];
            float p = v * v;
            r[l] = r[l] + p;
        }
    float res = ((r[0] + r[1]) + (r[2] + r[3])) + ((r[4] + r[5]) + (r[6] + r[7]));
#pragma unroll
    for (int d = 57; d < 64; ++d) { float v = xv[d]; float p = v * v; res = res + p; }
    float a0 = xv[0] * xv[0];
    return a0 + res;
}

__device__ __forceinline__ float np_blas_dot64(const float* __restrict__ xi_,
                                               const float* __restrict__ xj_) {
    float acc = 0.f;
#pragma unroll
    for (int d = 0; d < DIM; ++d) acc = fmaf(xi_[d], xj_[d], acc);
    return acc;
}
// =======================================================================

__global__ __launch_bounds__(NTHREADS, 3) void edge_knn_kernel(const float* __restrict__ x,
                                                               float* __restrict__ out) {
    // LDS: 8192 + 8704 + 128 + 256 + 28672 = 45952 B -> 3 blocks/CU
    __shared__ __align__(16) float sXiT[DIM * BI];    // [d][i]
    __shared__ __align__(16) float sXiRM[BI * RMP];   // [i][d]
    __shared__ float sSqni[BI];
    __shared__ float sSqnj[CJ];
    __shared__ __align__(16) float sU[7168];          // 28672 B union
    // phase1: xjT [64][66] = 4224 f, distT [32][66] = 2112 f  (6336 <= 7168)
    float* xjT   = sU;
    float* distT = sU + 4224;
    // phase2 overlay: mbk u32[256*24]=6144 w, pb int[256], sFin int[32*24]=768
    u32* mbk  = (u32*)sU;
    int* pb   = (int*)sU + 6144;
    int* sFin = (int*)sU + 6400;

    const int tid = threadIdx.x;
    const int blk = blockIdx.x;
    const int b   = blk / (NPTS / BI);
    const int i0  = (blk % (NPTS / BI)) * BI;
    const float* xb = x + (size_t)b * NPTS * DIM;

    // ---- stage central tile: transposed + row-major ----
    for (int idx = tid; idx < BI * (DIM / 4); idx += NTHREADS) {
        int ii = idx >> 4, c = idx & 15;
        float4 v = *(const float4*)(xb + (size_t)(i0 + ii) * DIM + c * 4);
        sXiT[(4 * c + 0) * BI + ii] = v.x;
        sXiT[(4 * c + 1) * BI + ii] = v.y;
        sXiT[(4 * c + 2) * BI + ii] = v.z;
        sXiT[(4 * c + 3) * BI + ii] = v.w;
        *(float4*)&sXiRM[ii * RMP + 4 * c] = v;
    }
    __syncthreads();
    if (tid < BI) {
        float s = 0.f;
        for (int d = 0; d < DIM; ++d) { float v = sXiT[d * BI + tid]; s = fmaf(v, v, s); }
        sSqni[tid] = s;
    }

    // stage-1 select state: u32 keys = (bits(dist+1) & 0xFFFFF000) | j12
    u32 lk[MCAND];
#pragma unroll
    for (int s = 0; s < MCAND; ++s) lk[s] = 0xFFFFFFFFu;
    u32 thr = 0xFFFFFFFFu;   // per-row shared threshold (upper bound on row 24th)

    const int a  = tid & 7;    // compute: i-group 4a..4a+3
    const int h  = tid >> 3;   // compute: j-pair 2h,2h+1 (h 0..31)
    const int si = tid >> 3;   // select/rescore: row
    const int st = tid & 7;    // select/rescore: 1/8 of row's j's

    for (int ch = 0; ch < NCHUNK; ++ch) {
        const int j0 = ch * CJ;
        // ---- stage xj chunk (transposed) + sqj via 16-lane shfl reduce ----
#pragma unroll
        for (int k = 0; k < 4; ++k) {
            int idx = tid + 256 * k;
            int r = idx >> 4, c = idx & 15;
            float4 v = *(const float4*)(xb + (size_t)(j0 + r) * DIM + c * 4);
            xjT[(4 * c + 0) * XJP + r] = v.x;
            xjT[(4 * c + 1) * XJP + r] = v.y;
            xjT[(4 * c + 2) * XJP + r] = v.z;
            xjT[(4 * c + 3) * XJP + r] = v.w;
            float ps = fmaf(v.x, v.x, fmaf(v.y, v.y, fmaf(v.z, v.z, v.w * v.w)));
            ps += __shfl_xor(ps, 1, 16);
            ps += __shfl_xor(ps, 2, 16);
            ps += __shfl_xor(ps, 4, 16);
            ps += __shfl_xor(ps, 8, 16);
            if ((tid & 15) == 0) sSqnj[r] = ps;
        }
        __syncthreads();   // xjT+sqnj ready; prev select done with distT

        // ---- compute 4i x 2j inner products ----
        float ac[4][2];
#pragma unroll
        for (int q = 0; q < 4; ++q) { ac[q][0] = 0.f; ac[q][1] = 0.f; }
#pragma unroll 16
        for (int d = 0; d < DIM; ++d) {
            float4 xi4 = *(const float4*)&sXiT[d * BI + 4 * a];
            float2 xj2 = *(const float2*)&xjT[d * XJP + 2 * h];
            ac[0][0] = fmaf(xi4.x, xj2.x, ac[0][0]);
            ac[1][0] = fmaf(xi4.y, xj2.x, ac[1][0]);
            ac[2][0] = fmaf(xi4.z, xj2.x, ac[2][0]);
            ac[3][0] = fmaf(xi4.w, xj2.x, ac[3][0]);
            ac[0][1] = fmaf(xi4.x, xj2.y, ac[0][1]);
            ac[1][1] = fmaf(xi4.y, xj2.y, ac[1][1]);
            ac[2][1] = fmaf(xi4.z, xj2.y, ac[2][1]);
            ac[3][1] = fmaf(xi4.w, xj2.y, ac[3][1]);
        }
        {
            float sq0 = sSqnj[2 * h], sq1 = sSqnj[2 * h + 1];
#pragma unroll
            for (int q = 0; q < 4; ++q) {
                float di = sSqni[4 * a + q];
                float2 o;
                o.x = di + sq0 - 2.f * ac[q][0];
                o.y = di + sq1 - 2.f * ac[q][1];
                *(float2*)&distT[(4 * a + q) * DTP + 2 * h] = o;
            }
        }
        __syncthreads();   // distT ready

        // ---- select: 8 j's per thread, u32 key sorted-insert w/ row threshold ----
        u32 g = min(lk[MCAND - 1], thr);
#pragma unroll
        for (int s2 = 0; s2 < 4; ++s2) {
            float2 dv2 = *(const float2*)&distT[si * DTP + st * 8 + 2 * s2];
#pragma unroll
            for (int w = 0; w < 2; ++w) {
                float dv = w ? dv2.y : dv2.x;
                u32 jg = (u32)(j0 + st * 8 + 2 * s2 + w);
                u32 kb = (__float_as_uint(dv + 1.0f) & 0xFFFFF000u) | jg;
                if (kb < g) {
                    u32 cur = kb;
#pragma unroll
                    for (int t = 0; t < MCAND; ++t) {
                        u32 lo = min(cur, lk[t]);
                        cur = max(cur, lk[t]);
                        lk[t] = lo;
                    }
                    g = min(lk[MCAND - 1], thr);
                }
            }
        }
        // update shared row threshold: min over the row's 8 threads of lk[23]
        u32 m = lk[MCAND - 1];
        m = min(m, (u32)__shfl_xor((int)m, 1, 8));
        m = min(m, (u32)__shfl_xor((int)m, 2, 8));
        m = min(m, (u32)__shfl_xor((int)m, 4, 8));
        thr = m;
    }
    __syncthreads();
    // ---- dump sorted lists into union (xjT/distT dead) ----
#pragma unroll
    for (int s = 0; s < MCAND; ++s) mbk[tid * MCAND + s] = lk[s];
    __syncthreads();
    // ---- 8-way merge per row -> top-24 candidate j's ----
    if (st == 0) {
        int* p = pb + si * 8;
        for (int t = 0; t < 8; ++t) p[t] = 0;
        for (int slot = 0; slot < MCAND; ++slot) {
            u32 best = 0xFFFFFFFFu; int bt = 0;
            for (int t = 0; t < 8; ++t) {
                int pt = p[t];
                if (pt < MCAND) {
                    u32 v = mbk[(si * 8 + t) * MCAND + pt];
                    if (v < best) { best = v; bt = t; }
                }
            }
            p[bt]++;
            sFin[si * MCAND + slot] = (int)(best & 0xFFFu);
        }
    }
    __syncthreads();
    // ---- rescore: VALIDATED R11 emulation (BLAS seq-FMA inner + np.sum sq) ----
    ull kk[3];
    {
        float xi_[DIM];
#pragma unroll
        for (int d4 = 0; d4 < DIM / 4; ++d4) {
            float4 v = *(const float4*)&sXiRM[si * RMP + 4 * d4];
            xi_[4 * d4 + 0] = v.x; xi_[4 * d4 + 1] = v.y;
            xi_[4 * d4 + 2] = v.z; xi_[4 * d4 + 3] = v.w;
        }
        const float sqi32 = np_sumsq64(xi_);
#pragma unroll
        for (int c = 0; c < 3; ++c) {
            const int j = sFin[si * MCAND + st * 3 + c];
            const float* pxj = xb + (size_t)j * DIM;
            float xj_[DIM];
#pragma unroll
            for (int d4 = 0; d4 < DIM / 4; ++d4) {
                float4 v = *(const float4*)(pxj + 4 * d4);
                xj_[4 * d4 + 0] = v.x; xj_[4 * d4 + 1] = v.y;
                xj_[4 * d4 + 2] = v.z; xj_[4 * d4 + 3] = v.w;
            }
            const float inn   = np_blas_dot64(xi_, xj_);
            const float sqj32 = np_sumsq64(xj_);
            float adj32;
            {
#pragma clang fp contract(off)
                adj32 = (sqi32 - 2.0f * inn) + sqj32;
            }
            unsigned int bits = __float_as_uint(adj32);
            unsigned int mu = (bits & 0x80000000u) ? ~bits : (bits | 0x80000000u);
            kk[c] = ((ull)mu << 32) | (unsigned int)j;
        }
    }
    // ---- top-20 via 8-lane group selection (emulated order, index tie-break) ----
    for (int k = 0; k < KNN; ++k) {
        ull m = kk[0] < kk[1] ? kk[0] : kk[1];
        m = m < kk[2] ? m : kk[2];
#pragma unroll
        for (int w = 1; w < 8; w <<= 1) {
            ull o = (ull)__shfl_xor((long long)m, w, 8);
            m = o < m ? o : m;
        }
#pragma unroll
        for (int c = 0; c < 3; ++c) if (kk[c] == m) kk[c] = ~0ull;
        if (st == 0) sFin[si * MCAND + k] = (int)(m & 0xFFFFFFFFull);
    }
    __syncthreads();
    // ---- fused emit: [i0..i0+31] x 20 x 128, coalesced float4 ----
    const size_t obase = (size_t)(b * NPTS + i0) * (KNN * 2 * DIM);
    for (int v = tid; v < BI * KNN * 2 * DIM / 4; v += NTHREADS) {
        int v4 = v * 4;
        int ii = v4 / (KNN * 2 * DIM);
        int r  = v4 % (KNN * 2 * DIM);
        int k  = r / (2 * DIM);
        int d  = r % (2 * DIM);
        float4 o;
        if (d < DIM) {
            o = *(const float4*)&sXiRM[ii * RMP + d];
        } else {
            int dd = d - DIM;
            int j  = sFin[ii * MCAND + k];
            float4 n4 = *(const float4*)(xb + (size_t)j * DIM + dd);
            float4 c4 = *(const float4*)&sXiRM[ii * RMP + dd];
            o.x = n4.x - c4.x;
            o.y = n4.y - c4.y;
            o.z = n4.z - c4.z;
            o.w = n4.w - c4.w;
        }
        *(float4*)(out + obase + v4) = o;
    }
}

extern "C" void kernel_launch(void* const* d_in, const int* in_sizes, int n_in,
                              void* d_out, int out_size, void* d_ws, size_t ws_size,
                              hipStream_t stream) {
    const float* x = (const float*)d_in[0];
    float* out = (float*)d_out;
    dim3 grid(BATCH * (NPTS / BI));
    hipLaunchKernelGGL(edge_knn_kernel, grid, dim3(NTHREADS), 0, stream, x, out);
}

// Round 13
// 551.416 us; speedup vs baseline: 3.1136x; 1.6887x over previous
//
#include <hip/hip_runtime.h>

#define BATCH 8
#define NPTS 4096
#define DIM 64
#define KNN 20
#define BI 32
#define CJ 128
#define MCAND 32
#define NTH 256
#define NCHUNK (NPTS / CJ)   // 32
#define XBP 36               // bf16 row pitch in u32 words (72 bf16)
#define DTP 132              // distT [i][j] pitch over j (f32)
#define MBS 33               // mbk per-thread stride
#define RESC (MCAND / 8)     // 4 rescore candidates per thread

typedef unsigned long long ull;
typedef unsigned int u32;
typedef __attribute__((ext_vector_type(8))) __bf16 bf16x8;
typedef __attribute__((ext_vector_type(16))) float f32x16;

union FragU { bf16x8 v; uint2 u2[2]; };

// ===== VALIDATED R11 recipes (bit-exact vs checker) — do not touch =====
__device__ __forceinline__ float np_sumsq64(const float* __restrict__ xv) {
#pragma clang fp contract(off)
    float r[8];
#pragma unroll
    for (int l = 0; l < 8; ++l) { float v = xv[1 + l]; r[l] = v * v; }
#pragma unroll
    for (int t = 1; t < 7; ++t)
#pragma unroll
        for (int l = 0; l < 8; ++l) {
            float v = xv[1 + 8 * t + l];
            float p = v * v;
            r[l] = r[l] + p;
        }
    float res = ((r[0] + r[1]) + (r[2] + r[3])) + ((r[4] + r[5]) + (r[6] + r[7]));
#pragma unroll
    for (int d = 57; d < 64; ++d) { float v = xv[d]; float p = v * v; res = res + p; }
    float a0 = xv[0] * xv[0];
    return a0 + res;
}

__device__ __forceinline__ float np_blas_dot64(const float* __restrict__ xi_,
                                               const float* __restrict__ xj_) {
    float acc = 0.f;
#pragma unroll
    for (int d = 0; d < DIM; ++d) acc = fmaf(xi_[d], xj_[d], acc);
    return acc;
}
// =======================================================================

__global__ __launch_bounds__(NTH, 3) void edge_knn_kernel(const float* __restrict__ x,
                                                          float* __restrict__ out) {
    // LDS: 39936 (pool) + 128 + 512 + 4096 + 1024 = 45696 B -> 3 blocks/CU
    __shared__ __align__(16) u32 sPool[9984];
    __shared__ __align__(16) float sSqni[BI];
    __shared__ __align__(16) float sSqnj[CJ];
    __shared__ int sFin[BI * MCAND];
    __shared__ int pb[BI * 8];

    u32* sXjB = sPool;                                   // [128][36] words
    u32* sXiB = sPool + CJ * XBP;                        // [32][36]
    float* distT = (float*)(sPool + CJ * XBP + BI * XBP);// [32][132] f32
    u32* mbk = sPool;                                    // overlay: 256*33 = 8448 <= 9984

    const int tid = threadIdx.x;
    const int blk = blockIdx.x;
    const int b   = blk / (NPTS / BI);
    const int i0  = (blk % (NPTS / BI)) * BI;
    const float* xb = x + (size_t)b * NPTS * DIM;

    const int r2 = tid >> 1, h2 = tid & 1;

    // stage one 128-row j-chunk: f32 global -> bf16(trunc) LDS (swizzled) + sqnj(f32)
    auto stageXj = [&](int ch) {
        const float* src = xb + (size_t)(ch * CJ + r2) * DIM + h2 * 32;
        u32* dst = sXjB + r2 * XBP;
        const u32 swz = ((u32)(r2 >> 3) & 3u) << 2;
        float ps = 0.f;
#pragma unroll
        for (int q = 0; q < 4; ++q) {
            float4 va = *(const float4*)(src + q * 8);
            float4 vb = *(const float4*)(src + q * 8 + 4);
            ps = fmaf(va.x, va.x, ps); ps = fmaf(va.y, va.y, ps);
            ps = fmaf(va.z, va.z, ps); ps = fmaf(va.w, va.w, ps);
            ps = fmaf(vb.x, vb.x, ps); ps = fmaf(vb.y, vb.y, ps);
            ps = fmaf(vb.z, vb.z, ps); ps = fmaf(vb.w, vb.w, ps);
            uint4 pk;
            pk.x = (__float_as_uint(va.y) & 0xFFFF0000u) | (__float_as_uint(va.x) >> 16);
            pk.y = (__float_as_uint(va.w) & 0xFFFF0000u) | (__float_as_uint(va.z) >> 16);
            pk.z = (__float_as_uint(vb.y) & 0xFFFF0000u) | (__float_as_uint(vb.x) >> 16);
            pk.w = (__float_as_uint(vb.w) & 0xFFFF0000u) | (__float_as_uint(vb.z) >> 16);
            *(uint4*)&dst[(u32)(h2 * 16 + q * 4) ^ swz] = pk;
        }
        ps += __shfl_xor(ps, 1, 2);
        if (h2 == 0) sSqnj[r2] = ps;
    };

    // ---- prologue: xi bf16 tile + sqni + first j-chunk ----
    if (tid < 2 * BI) {
        const float* src = xb + (size_t)(i0 + r2) * DIM + h2 * 32;
        u32* dst = sXiB + r2 * XBP;
        const u32 swz = ((u32)(r2 >> 3) & 3u) << 2;
#pragma unroll
        for (int q = 0; q < 4; ++q) {
            float4 va = *(const float4*)(src + q * 8);
            float4 vb = *(const float4*)(src + q * 8 + 4);
            uint4 pk;
            pk.x = (__float_as_uint(va.y) & 0xFFFF0000u) | (__float_as_uint(va.x) >> 16);
            pk.y = (__float_as_uint(va.w) & 0xFFFF0000u) | (__float_as_uint(va.z) >> 16);
            pk.z = (__float_as_uint(vb.y) & 0xFFFF0000u) | (__float_as_uint(vb.x) >> 16);
            pk.w = (__float_as_uint(vb.w) & 0xFFFF0000u) | (__float_as_uint(vb.z) >> 16);
            *(uint4*)&dst[(u32)(h2 * 16 + q * 4) ^ swz] = pk;
        }
    }
    if (tid < BI) {
        const float* p = xb + (size_t)(i0 + tid) * DIM;
        float s = 0.f;
#pragma unroll
        for (int d4 = 0; d4 < 16; ++d4) {
            float4 v = *(const float4*)(p + 4 * d4);
            s = fmaf(v.x, v.x, s); s = fmaf(v.y, v.y, s);
            s = fmaf(v.z, v.z, s); s = fmaf(v.w, v.w, s);
        }
        sSqni[tid] = s;
    }
    stageXj(0);
    __syncthreads();

    // stage-1 select state
    u32 lk[MCAND];
#pragma unroll
    for (int s = 0; s < MCAND; ++s) lk[s] = 0xFFFFFFFFu;
    u32 thr = 0xFFFFFFFFu;

    const int lane = tid & 63;
    const int wv   = tid >> 6;        // wave -> j-tile
    const int nrow = lane & 31;
    const int hf   = lane >> 5;
    const int si   = tid >> 3;        // select/rescore row
    const int st   = tid & 7;

    const u32* aRow = sXiB + nrow * XBP;
    const u32* bRow = sXjB + (wv * 32 + nrow) * XBP;
    const u32 swzf  = ((u32)(nrow >> 3) & 3u) << 2;   // same key for A and B rows
    const int jloc  = wv * 32 + nrow;

    for (int ch = 0; ch < NCHUNK; ++ch) {
        // ---- MFMA: S = Xi(32x64) * Xj^T, wave's 32x32 tile, K=64 in 4 steps ----
        f32x16 acc;
#pragma unroll
        for (int e = 0; e < 16; ++e) acc[e] = 0.f;
#pragma unroll
        for (int ks = 0; ks < 4; ++ks) {
            const int w0 = ks * 8 + 2 * hf;
            FragU A, B;
            A.u2[0] = *(const uint2*)&aRow[(u32)w0 ^ swzf];
            A.u2[1] = *(const uint2*)&aRow[(u32)(w0 + 4) ^ swzf];
            B.u2[0] = *(const uint2*)&bRow[(u32)w0 ^ swzf];
            B.u2[1] = *(const uint2*)&bRow[(u32)(w0 + 4) ^ swzf];
            acc = __builtin_amdgcn_mfma_f32_32x32x16_bf16(A.v, B.v, acc, 0, 0, 0);
        }
        {   // dist = sqi + sqj - 2*inner -> distT[i][j] (conflict-free b32 writes)
            const float sqj = sSqnj[jloc];
            float* dT = distT + jloc;
#pragma unroll
            for (int gp = 0; gp < 4; ++gp) {
                const int rb = 8 * gp + 4 * hf;   // C/D row = (reg&3)+8*(reg>>2)+4*(lane>>5)
                float4 s4 = *(const float4*)&sSqni[rb];
                dT[(rb + 0) * DTP] = fmaf(-2.f, acc[4 * gp + 0], s4.x + sqj);
                dT[(rb + 1) * DTP] = fmaf(-2.f, acc[4 * gp + 1], s4.y + sqj);
                dT[(rb + 2) * DTP] = fmaf(-2.f, acc[4 * gp + 2], s4.z + sqj);
                dT[(rb + 3) * DTP] = fmaf(-2.f, acc[4 * gp + 3], s4.w + sqj);
            }
        }
        __syncthreads();
        // ---- issue next-chunk staging early (HBM hides under select) ----
        if (ch + 1 < NCHUNK) stageXj(ch + 1);
        // ---- select: 16 j's per thread, u32 keys, row-threshold guard ----
        {
            const int j0 = ch * CJ;
            u32 gte = min(lk[MCAND - 1], thr);
            const float* drow = distT + si * DTP;
#pragma unroll
            for (int s2 = 0; s2 < 4; ++s2) {
                float4 dv4 = *(const float4*)&drow[st * 16 + 4 * s2];
#pragma unroll
                for (int e = 0; e < 4; ++e) {
                    float dv = e == 0 ? dv4.x : e == 1 ? dv4.y : e == 2 ? dv4.z : dv4.w;
                    u32 kb = (__float_as_uint(dv + 1.0f) & 0xFFFFF000u) |
                             (u32)(j0 + st * 16 + 4 * s2 + e);
                    if (kb < gte) {
                        u32 cur = kb;
#pragma unroll
                        for (int t = 0; t < MCAND; ++t) {
                            u32 lo = min(cur, lk[t]);
                            cur = max(cur, lk[t]);
                            lk[t] = lo;
                        }
                        gte = min(lk[MCAND - 1], thr);
                    }
                }
            }
            u32 m = lk[MCAND - 1];
            m = min(m, (u32)__shfl_xor((int)m, 1, 8));
            m = min(m, (u32)__shfl_xor((int)m, 2, 8));
            m = min(m, (u32)__shfl_xor((int)m, 4, 8));
            thr = m;
        }
        __syncthreads();
    }

    // ---- dump sorted lists (pool buffers dead) ----
#pragma unroll
    for (int s = 0; s < MCAND; ++s) mbk[tid * MBS + s] = lk[s];
    __syncthreads();
    // ---- 8-way merge per row -> top-32 candidate j's ----
    if (st == 0) {
        int* p = pb + si * 8;
        for (int t = 0; t < 8; ++t) p[t] = 0;
        for (int slot = 0; slot < MCAND; ++slot) {
            u32 best = 0xFFFFFFFFu; int bt = 0;
            for (int t = 0; t < 8; ++t) {
                int pt = p[t];
                if (pt < MCAND) {
                    u32 v = mbk[(si * 8 + t) * MBS + pt];
                    if (v < best) { best = v; bt = t; }
                }
            }
            p[bt]++;
            sFin[si * MCAND + slot] = (int)(best & 0xFFFu);
        }
    }
    __syncthreads();

    // ---- rescore: VALIDATED R11 emulation, 4 cands/thread ----
    ull kk[RESC];
    {
        float xi_[DIM];
        const float* pxi = xb + (size_t)(i0 + si) * DIM;
#pragma unroll
        for (int d4 = 0; d4 < DIM / 4; ++d4) {
            float4 v = *(const float4*)(pxi + 4 * d4);
            xi_[4 * d4 + 0] = v.x; xi_[4 * d4 + 1] = v.y;
            xi_[4 * d4 + 2] = v.z; xi_[4 * d4 + 3] = v.w;
        }
        const float sqi32 = np_sumsq64(xi_);
#pragma unroll
        for (int c = 0; c < RESC; ++c) {
            const int j = sFin[si * MCAND + st * RESC + c];
            const float* pxj = xb + (size_t)j * DIM;
            float xj_[DIM];
#pragma unroll
            for (int d4 = 0; d4 < DIM / 4; ++d4) {
                float4 v = *(const float4*)(pxj + 4 * d4);
                xj_[4 * d4 + 0] = v.x; xj_[4 * d4 + 1] = v.y;
                xj_[4 * d4 + 2] = v.z; xj_[4 * d4 + 3] = v.w;
            }
            const float inn   = np_blas_dot64(xi_, xj_);
            const float sqj32 = np_sumsq64(xj_);
            float adj32;
            {
#pragma clang fp contract(off)
                adj32 = (sqi32 - 2.0f * inn) + sqj32;
            }
            u32 bits = __float_as_uint(adj32);
            u32 mu = (bits & 0x80000000u) ? ~bits : (bits | 0x80000000u);
            kk[c] = ((ull)mu << 32) | (u32)j;
        }
    }
    // ---- top-20 via 8-lane group selection (emulated order, index tie-break) ----
    for (int k = 0; k < KNN; ++k) {
        ull m01 = kk[0] < kk[1] ? kk[0] : kk[1];
        ull m23 = kk[2] < kk[3] ? kk[2] : kk[3];
        ull m = m01 < m23 ? m01 : m23;
#pragma unroll
        for (int w = 1; w < 8; w <<= 1) {
            ull o = (ull)__shfl_xor((long long)m, w, 8);
            m = o < m ? o : m;
        }
#pragma unroll
        for (int c = 0; c < RESC; ++c) if (kk[c] == m) kk[c] = ~0ull;
        if (st == 0) sFin[si * MCAND + k] = (int)(m & 0xFFFFFFFFull);
    }
    __syncthreads();
    // ---- fused emit: [i0..i0+31] x 20 x 128, coalesced float4 ----
    const size_t obase = (size_t)(b * NPTS + i0) * (KNN * 2 * DIM);
    for (int v = tid; v < BI * KNN * 2 * DIM / 4; v += NTH) {
        int v4 = v * 4;
        int ii = v4 / (KNN * 2 * DIM);
        int rr = v4 % (KNN * 2 * DIM);
        int k  = rr / (2 * DIM);
        int d  = rr % (2 * DIM);
        const float* crow = xb + (size_t)(i0 + ii) * DIM;
        float4 o;
        if (d < DIM) {
            o = *(const float4*)(crow + d);
        } else {
            int dd = d - DIM;
            int j  = sFin[ii * MCAND + k];
            float4 n4 = *(const float4*)(xb + (size_t)j * DIM + dd);
            float4 c4 = *(const float4*)(crow + dd);
            o.x = n4.x - c4.x;
            o.y = n4.y - c4.y;
            o.z = n4.z - c4.z;
            o.w = n4.w - c4.w;
        }
        *(float4*)(out + obase + v4) = o;
    }
}

extern "C" void kernel_launch(void* const* d_in, const int* in_sizes, int n_in,
                              void* d_out, int out_size, void* d_ws, size_t ws_size,
                              hipStream_t stream) {
    const float* x = (const float*)d_in[0];
    float* out = (float*)d_out;
    dim3 grid(BATCH * (NPTS / BI));
    hipLaunchKernelGGL(edge_knn_kernel, grid, dim3(NTH), 0, stream, x, out);
}

// Round 14
// 463.813 us; speedup vs baseline: 3.7017x; 1.1889x over previous
//
#include <hip/hip_runtime.h>

#define BATCH 8
#define NPTS 4096
#define DIM 64
#define KNN 20
#define BI 32
#define CJ 128
#define MCT 16               // per-thread sorted list
#define MROW 32              // row candidate count after merge
#define NTH 256
#define NCHUNK (NPTS / CJ)   // 32
#define XBP 36               // bf16 row pitch in u32 words
#define QST 132              // queue row stride (u32), conflict-free
#define MBS 17               // mbk per-thread stride
#define RESC 4               // rescore candidates per thread

typedef unsigned long long ull;
typedef unsigned int u32;
typedef __attribute__((ext_vector_type(8))) __bf16 bf16x8;
typedef __attribute__((ext_vector_type(16))) float f32x16;

union FragU { bf16x8 v; uint2 u2[2]; };

// ===== VALIDATED R11 recipes (bit-exact vs checker) — do not touch =====
__device__ __forceinline__ float np_sumsq64(const float* __restrict__ xv) {
#pragma clang fp contract(off)
    float r[8];
#pragma unroll
    for (int l = 0; l < 8; ++l) { float v = xv[1 + l]; r[l] = v * v; }
#pragma unroll
    for (int t = 1; t < 7; ++t)
#pragma unroll
        for (int l = 0; l < 8; ++l) {
            float v = xv[1 + 8 * t + l];
            float p = v * v;
            r[l] = r[l] + p;
        }
    float res = ((r[0] + r[1]) + (r[2] + r[3])) + ((r[4] + r[5]) + (r[6] + r[7]));
#pragma unroll
    for (int d = 57; d < 64; ++d) { float v = xv[d]; float p = v * v; res = res + p; }
    float a0 = xv[0] * xv[0];
    return a0 + res;
}

__device__ __forceinline__ float np_blas_dot64(const float* __restrict__ xi_,
                                               const float* __restrict__ xj_) {
    float acc = 0.f;
#pragma unroll
    for (int d = 0; d < DIM; ++d) acc = fmaf(xi_[d], xj_[d], acc);
    return acc;
}
// =======================================================================

__global__ __launch_bounds__(NTH, 3) void edge_knn_kernel(const float* __restrict__ x,
                                                          float* __restrict__ out) {
    // LDS: 39936 + 128 + 512 + 4096 + 128 + 128 = 44928 B -> 3 blocks/CU
    __shared__ __align__(16) u32 sPool[9984];
    __shared__ __align__(16) float sSqni[BI];
    __shared__ __align__(16) float sSqnj[CJ];
    __shared__ int sFin[BI * MROW];
    __shared__ int qcnt[BI];
    __shared__ __align__(16) u32 thrq[BI];

    u32* sXjB = sPool;               // [128][36]
    u32* sXiB = sPool + CJ * XBP;    // [32][36]
    u32* sQ   = sPool + CJ * XBP + BI * XBP;   // [32][132]
    u32* mbk  = sPool;               // overlay after loop: 256*17 = 4352 words

    const int tid = threadIdx.x;
    const int blk = blockIdx.x;
    const int b   = blk / (NPTS / BI);
    const int i0  = (blk % (NPTS / BI)) * BI;
    const float* xb = x + (size_t)b * NPTS * DIM;

    const int r2 = tid >> 1, h2 = tid & 1;

    auto stageXj = [&](int ch) {
        const float* src = xb + (size_t)(ch * CJ + r2) * DIM + h2 * 32;
        u32* dst = sXjB + r2 * XBP;
        const u32 swz = ((u32)(r2 >> 3) & 3u) << 2;
        float ps = 0.f;
#pragma unroll
        for (int q = 0; q < 4; ++q) {
            float4 va = *(const float4*)(src + q * 8);
            float4 vb = *(const float4*)(src + q * 8 + 4);
            ps = fmaf(va.x, va.x, ps); ps = fmaf(va.y, va.y, ps);
            ps = fmaf(va.z, va.z, ps); ps = fmaf(va.w, va.w, ps);
            ps = fmaf(vb.x, vb.x, ps); ps = fmaf(vb.y, vb.y, ps);
            ps = fmaf(vb.z, vb.z, ps); ps = fmaf(vb.w, vb.w, ps);
            uint4 pk;
            pk.x = (__float_as_uint(va.y) & 0xFFFF0000u) | (__float_as_uint(va.x) >> 16);
            pk.y = (__float_as_uint(va.w) & 0xFFFF0000u) | (__float_as_uint(va.z) >> 16);
            pk.z = (__float_as_uint(vb.y) & 0xFFFF0000u) | (__float_as_uint(vb.x) >> 16);
            pk.w = (__float_as_uint(vb.w) & 0xFFFF0000u) | (__float_as_uint(vb.z) >> 16);
            *(uint4*)&dst[(u32)(h2 * 16 + q * 4) ^ swz] = pk;
        }
        ps += __shfl_xor(ps, 1, 2);
        if (h2 == 0) sSqnj[r2] = ps;
    };

    // ---- prologue ----
    if (tid < 2 * BI) {
        const float* src = xb + (size_t)(i0 + r2) * DIM + h2 * 32;
        u32* dst = sXiB + r2 * XBP;
        const u32 swz = ((u32)(r2 >> 3) & 3u) << 2;
#pragma unroll
        for (int q = 0; q < 4; ++q) {
            float4 va = *(const float4*)(src + q * 8);
            float4 vb = *(const float4*)(src + q * 8 + 4);
            uint4 pk;
            pk.x = (__float_as_uint(va.y) & 0xFFFF0000u) | (__float_as_uint(va.x) >> 16);
            pk.y = (__float_as_uint(va.w) & 0xFFFF0000u) | (__float_as_uint(va.z) >> 16);
            pk.z = (__float_as_uint(vb.y) & 0xFFFF0000u) | (__float_as_uint(vb.x) >> 16);
            pk.w = (__float_as_uint(vb.w) & 0xFFFF0000u) | (__float_as_uint(vb.z) >> 16);
            *(uint4*)&dst[(u32)(h2 * 16 + q * 4) ^ swz] = pk;
        }
    }
    if (tid < BI) {
        const float* p = xb + (size_t)(i0 + tid) * DIM;
        float s = 0.f;
#pragma unroll
        for (int d4 = 0; d4 < 16; ++d4) {
            float4 v = *(const float4*)(p + 4 * d4);
            s = fmaf(v.x, v.x, s); s = fmaf(v.y, v.y, s);
            s = fmaf(v.z, v.z, s); s = fmaf(v.w, v.w, s);
        }
        sSqni[tid] = s;
        qcnt[tid] = 0;
        thrq[tid] = 0xFFFFFFFFu;
    }
    stageXj(0);
    __syncthreads();

    u32 lk[MCT];
#pragma unroll
    for (int s = 0; s < MCT; ++s) lk[s] = 0xFFFFFFFFu;

    const int lane = tid & 63;
    const int wv   = tid >> 6;
    const int nrow = lane & 31;
    const int hf   = lane >> 5;
    const int si   = tid >> 3;
    const int st   = tid & 7;

    const u32* aRow = sXiB + nrow * XBP;
    const u32* bRow = sXjB + (wv * 32 + nrow) * XBP;
    const u32 swzf  = ((u32)(nrow >> 3) & 3u) << 2;
    const int jloc  = wv * 32 + nrow;

    for (int ch = 0; ch < NCHUNK; ++ch) {
        // ---- MFMA: wave's 32x32 Gram tile, K=64 ----
        f32x16 acc;
#pragma unroll
        for (int e = 0; e < 16; ++e) acc[e] = 0.f;
#pragma unroll
        for (int ks = 0; ks < 4; ++ks) {
            const int w0 = ks * 8 + 2 * hf;
            FragU A, B;
            A.u2[0] = *(const uint2*)&aRow[(u32)w0 ^ swzf];
            A.u2[1] = *(const uint2*)&aRow[(u32)(w0 + 4) ^ swzf];
            B.u2[0] = *(const uint2*)&bRow[(u32)w0 ^ swzf];
            B.u2[1] = *(const uint2*)&bRow[(u32)(w0 + 4) ^ swzf];
            acc = __builtin_amdgcn_mfma_f32_32x32x16_bf16(A.v, B.v, acc, 0, 0, 0);
        }
        // ---- epilogue: threshold-filter + queue push ----
        {
            const u32 jg = (u32)(ch * CJ + jloc);
            const float sqj = sSqnj[jloc];
#pragma unroll
            for (int gp = 0; gp < 4; ++gp) {
                const int rb = 8 * gp + 4 * hf;
                float4 s4 = *(const float4*)&sSqni[rb];
                uint4 t4 = *(const uint4*)&thrq[rb];
#pragma unroll
                for (int e = 0; e < 4; ++e) {
                    float se = e == 0 ? s4.x : e == 1 ? s4.y : e == 2 ? s4.z : s4.w;
                    u32 te = e == 0 ? t4.x : e == 1 ? t4.y : e == 2 ? t4.z : t4.w;
                    float dist = fmaf(-2.f, acc[4 * gp + e], se + sqj);
                    u32 kb = (__float_as_uint(dist + 1.0f) & 0xFFFFF000u) | jg;
                    if (kb < te) {
                        int idx = atomicAdd(&qcnt[rb + e], 1);
                        sQ[(rb + e) * QST + idx] = kb;
                    }
                }
            }
        }
        __syncthreads();   // (1) queue complete; sXjB frag reads done
        if (ch + 1 < NCHUNK) stageXj(ch + 1);
        // ---- flush: insert queue entries into per-thread sorted-16 ----
        u32 gte;
        {
            int cnt = qcnt[si];
            gte = lk[MCT - 1];
            for (int q = st; q < cnt; q += 8) {
                u32 kb = sQ[si * QST + q];
                if (kb < gte) {
                    u32 cur = kb;
#pragma unroll
                    for (int t = 0; t < MCT; ++t) {
                        u32 lo = min(cur, lk[t]);
                        cur = max(cur, lk[t]);
                        lk[t] = lo;
                    }
                    gte = lk[MCT - 1];
                }
            }
        }
        {   // row threshold = min over 8 threads of their 16th
            u32 m = gte;
            m = min(m, (u32)__shfl_xor((int)m, 1, 8));
            m = min(m, (u32)__shfl_xor((int)m, 2, 8));
            m = min(m, (u32)__shfl_xor((int)m, 4, 8));
            __syncthreads();   // (2) queue reads done
            if (st == 0) { thrq[si] = m; qcnt[si] = 0; }
        }
        __syncthreads();       // (3) reset visible before next epilogue
    }

    // ---- dump sorted lists (pool dead) ----
#pragma unroll
    for (int s = 0; s < MCT; ++s) mbk[tid * MBS + s] = lk[s];
    __syncthreads();
    // ---- 8-way merge per row -> top-32 candidate j's ----
    if (st == 0) {
        int p[8];
#pragma unroll
        for (int t = 0; t < 8; ++t) p[t] = 0;
        for (int slot = 0; slot < MROW; ++slot) {
            u32 best = 0xFFFFFFFFu; int bt = 0;
#pragma unroll
            for (int t = 0; t < 8; ++t) {
                int pt = p[t];
                u32 v = (pt < MCT) ? mbk[(si * 8 + t) * MBS + pt] : 0xFFFFFFFFu;
                if (v < best) { best = v; bt = t; }
            }
            p[bt]++;
            sFin[si * MROW + slot] = (int)(best & 0xFFFu);
        }
    }
    __syncthreads();

    // ---- rescore: VALIDATED R11 emulation, 4 cands/thread ----
    ull kk[RESC];
    {
        float xi_[DIM];
        const float* pxi = xb + (size_t)(i0 + si) * DIM;
#pragma unroll
        for (int d4 = 0; d4 < DIM / 4; ++d4) {
            float4 v = *(const float4*)(pxi + 4 * d4);
            xi_[4 * d4 + 0] = v.x; xi_[4 * d4 + 1] = v.y;
            xi_[4 * d4 + 2] = v.z; xi_[4 * d4 + 3] = v.w;
        }
        const float sqi32 = np_sumsq64(xi_);
#pragma unroll
        for (int c = 0; c < RESC; ++c) {
            const int j = sFin[si * MROW + st * RESC + c];
            const float* pxj = xb + (size_t)j * DIM;
            float xj_[DIM];
#pragma unroll
            for (int d4 = 0; d4 < DIM / 4; ++d4) {
                float4 v = *(const float4*)(pxj + 4 * d4);
                xj_[4 * d4 + 0] = v.x; xj_[4 * d4 + 1] = v.y;
                xj_[4 * d4 + 2] = v.z; xj_[4 * d4 + 3] = v.w;
            }
            const float inn   = np_blas_dot64(xi_, xj_);
            const float sqj32 = np_sumsq64(xj_);
            float adj32;
            {
#pragma clang fp contract(off)
                adj32 = (sqi32 - 2.0f * inn) + sqj32;
            }
            u32 bits = __float_as_uint(adj32);
            u32 mu = (bits & 0x80000000u) ? ~bits : (bits | 0x80000000u);
            kk[c] = ((ull)mu << 32) | (u32)j;
        }
    }
    for (int k = 0; k < KNN; ++k) {
        ull m01 = kk[0] < kk[1] ? kk[0] : kk[1];
        ull m23 = kk[2] < kk[3] ? kk[2] : kk[3];
        ull m = m01 < m23 ? m01 : m23;
#pragma unroll
        for (int w = 1; w < 8; w <<= 1) {
            ull o = (ull)__shfl_xor((long long)m, w, 8);
            m = o < m ? o : m;
        }
#pragma unroll
        for (int c = 0; c < RESC; ++c) if (kk[c] == m) kk[c] = ~0ull;
        if (st == 0) sFin[si * MROW + k] = (int)(m & 0xFFFFFFFFull);
    }
    __syncthreads();
    // ---- fused emit ----
    const size_t obase = (size_t)(b * NPTS + i0) * (KNN * 2 * DIM);
    for (int v = tid; v < BI * KNN * 2 * DIM / 4; v += NTH) {
        int v4 = v * 4;
        int ii = v4 / (KNN * 2 * DIM);
        int rr = v4 % (KNN * 2 * DIM);
        int k  = rr / (2 * DIM);
        int d  = rr % (2 * DIM);
        const float* crow = xb + (size_t)(i0 + ii) * DIM;
        float4 o;
        if (d < DIM) {
            o = *(const float4*)(crow + d);
        } else {
            int dd = d - DIM;
            int j  = sFin[ii * MROW + k];
            float4 n4 = *(const float4*)(xb + (size_t)j * DIM + dd);
            float4 c4 = *(const float4*)(crow + dd);
            o.x = n4.x - c4.x;
            o.y = n4.y - c4.y;
            o.z = n4.z - c4.z;
            o.w = n4.w - c4.w;
        }
        *(float4*)(out + obase + v4) = o;
    }
}

extern "C" void kernel_launch(void* const* d_in, const int* in_sizes, int n_in,
                              void* d_out, int out_size, void* d_ws, size_t ws_size,
                              hipStream_t stream) {
    const float* x = (const float*)d_in[0];
    float* out = (float*)d_out;
    dim3 grid(BATCH * (NPTS / BI));
    hipLaunchKernelGGL(edge_knn_kernel, grid, dim3(NTH), 0, stream, x, out);
}

// Round 15
// 383.465 us; speedup vs baseline: 4.4773x; 1.2095x over previous
//
#include <hip/hip_runtime.h>

#define BATCH 8
#define NPTS 4096
#define DIM 64
#define KNN 20
#define BI 32
#define CJ 128
#define MCT 16               // per-thread sorted list
#define MROW 32              // row candidate count after merge
#define NTH 256
#define NCHUNK (NPTS / CJ)   // 32
#define XBP 36               // bf16 row pitch in u32 words
#define QST 132              // queue row stride (u32)
#define MBS 17               // mbk per-thread stride
#define RESC 4               // rescore candidates per thread

typedef unsigned long long ull;
typedef unsigned int u32;
typedef __attribute__((ext_vector_type(8))) __bf16 bf16x8;
typedef __attribute__((ext_vector_type(16))) float f32x16;

union FragU { bf16x8 v; uint2 u2[2]; };

// ===== VALIDATED R11 recipes (bit-exact vs checker) — do not touch =====
__device__ __forceinline__ float np_sumsq64(const float* __restrict__ xv) {
#pragma clang fp contract(off)
    float r[8];
#pragma unroll
    for (int l = 0; l < 8; ++l) { float v = xv[1 + l]; r[l] = v * v; }
#pragma unroll
    for (int t = 1; t < 7; ++t)
#pragma unroll
        for (int l = 0; l < 8; ++l) {
            float v = xv[1 + 8 * t + l];
            float p = v * v;
            r[l] = r[l] + p;
        }
    float res = ((r[0] + r[1]) + (r[2] + r[3])) + ((r[4] + r[5]) + (r[6] + r[7]));
#pragma unroll
    for (int d = 57; d < 64; ++d) { float v = xv[d]; float p = v * v; res = res + p; }
    float a0 = xv[0] * xv[0];
    return a0 + res;
}

__device__ __forceinline__ float np_blas_dot64(const float* __restrict__ xi_,
                                               const float* __restrict__ xj_) {
    float acc = 0.f;
#pragma unroll
    for (int d = 0; d < DIM; ++d) acc = fmaf(xi_[d], xj_[d], acc);
    return acc;
}
// =======================================================================

__global__ __launch_bounds__(NTH, 4) void edge_knn_kernel(const float* __restrict__ x,
                                                          float* __restrict__ out) {
    // LDS: 39936 (pool) + 128 + 512 + 128 + 128 = 40832 B -> 4 blocks/CU
    __shared__ __align__(16) u32 sPool[9984];
    __shared__ __align__(16) float sSqni[BI];
    __shared__ __align__(16) float sSqnj[CJ];
    __shared__ int qcnt[BI];
    __shared__ __align__(16) u32 thrq[BI];

    u32* sXjB = sPool;               // [128][36]
    u32* sXiB = sPool + CJ * XBP;    // [32][36]
    u32* sQ   = sPool + CJ * XBP + BI * XBP;   // [32][132]
    u32* mbk  = sPool;               // overlay after loop: 256*17 = 4352 words
    int* sFin = (int*)(sPool + 4352);// overlay: 32*32 = 1024 words

    const int tid = threadIdx.x;
    const int blk = blockIdx.x;
    const int b   = blk / (NPTS / BI);
    const int i0  = (blk % (NPTS / BI)) * BI;
    const float* xb = x + (size_t)b * NPTS * DIM;

    const int r2 = tid >> 1, h2 = tid & 1;

    auto stageXj = [&](int ch) {
        const float* src = xb + (size_t)(ch * CJ + r2) * DIM + h2 * 32;
        u32* dst = sXjB + r2 * XBP;
        const u32 swz = ((u32)(r2 >> 3) & 3u) << 2;
        float ps = 0.f;
#pragma unroll
        for (int q = 0; q < 4; ++q) {
            float4 va = *(const float4*)(src + q * 8);
            float4 vb = *(const float4*)(src + q * 8 + 4);
            ps = fmaf(va.x, va.x, ps); ps = fmaf(va.y, va.y, ps);
            ps = fmaf(va.z, va.z, ps); ps = fmaf(va.w, va.w, ps);
            ps = fmaf(vb.x, vb.x, ps); ps = fmaf(vb.y, vb.y, ps);
            ps = fmaf(vb.z, vb.z, ps); ps = fmaf(vb.w, vb.w, ps);
            uint4 pk;
            pk.x = (__float_as_uint(va.y) & 0xFFFF0000u) | (__float_as_uint(va.x) >> 16);
            pk.y = (__float_as_uint(va.w) & 0xFFFF0000u) | (__float_as_uint(va.z) >> 16);
            pk.z = (__float_as_uint(vb.y) & 0xFFFF0000u) | (__float_as_uint(vb.x) >> 16);
            pk.w = (__float_as_uint(vb.w) & 0xFFFF0000u) | (__float_as_uint(vb.z) >> 16);
            *(uint4*)&dst[(u32)(h2 * 16 + q * 4) ^ swz] = pk;
        }
        ps += __shfl_xor(ps, 1, 2);
        if (h2 == 0) sSqnj[r2] = ps;
    };

    // ---- prologue ----
    if (tid < 2 * BI) {
        const float* src = xb + (size_t)(i0 + r2) * DIM + h2 * 32;
        u32* dst = sXiB + r2 * XBP;
        const u32 swz = ((u32)(r2 >> 3) & 3u) << 2;
#pragma unroll
        for (int q = 0; q < 4; ++q) {
            float4 va = *(const float4*)(src + q * 8);
            float4 vb = *(const float4*)(src + q * 8 + 4);
            uint4 pk;
            pk.x = (__float_as_uint(va.y) & 0xFFFF0000u) | (__float_as_uint(va.x) >> 16);
            pk.y = (__float_as_uint(va.w) & 0xFFFF0000u) | (__float_as_uint(va.z) >> 16);
            pk.z = (__float_as_uint(vb.y) & 0xFFFF0000u) | (__float_as_uint(vb.x) >> 16);
            pk.w = (__float_as_uint(vb.w) & 0xFFFF0000u) | (__float_as_uint(vb.z) >> 16);
            *(uint4*)&dst[(u32)(h2 * 16 + q * 4) ^ swz] = pk;
        }
    }
    if (tid < BI) {
        const float* p = xb + (size_t)(i0 + tid) * DIM;
        float s = 0.f;
#pragma unroll
        for (int d4 = 0; d4 < 16; ++d4) {
            float4 v = *(const float4*)(p + 4 * d4);
            s = fmaf(v.x, v.x, s); s = fmaf(v.y, v.y, s);
            s = fmaf(v.z, v.z, s); s = fmaf(v.w, v.w, s);
        }
        sSqni[tid] = s;
        qcnt[tid] = 0;
        thrq[tid] = 0xFFFFFFFFu;
    }
    stageXj(0);
    __syncthreads();

    u32 lk[MCT];
#pragma unroll
    for (int s = 0; s < MCT; ++s) lk[s] = 0xFFFFFFFFu;

    const int lane = tid & 63;
    const int wv   = tid >> 6;
    const int nrow = lane & 31;
    const int hf   = lane >> 5;
    const int si   = tid >> 3;
    const int st   = tid & 7;

    const u32* aRow = sXiB + nrow * XBP;
    const u32* bRow = sXjB + (wv * 32 + nrow) * XBP;
    const u32 swzf  = ((u32)(nrow >> 3) & 3u) << 2;
    const int jloc  = wv * 32 + nrow;
    const u32 lmask = (1u << (lane & 31)) - 1u;

    for (int ch = 0; ch < NCHUNK; ++ch) {
        // ---- MFMA: wave's 32x32 Gram tile, K=64 ----
        f32x16 acc;
#pragma unroll
        for (int e = 0; e < 16; ++e) acc[e] = 0.f;
#pragma unroll
        for (int ks = 0; ks < 4; ++ks) {
            const int w0 = ks * 8 + 2 * hf;
            FragU A, B;
            A.u2[0] = *(const uint2*)&aRow[(u32)w0 ^ swzf];
            A.u2[1] = *(const uint2*)&aRow[(u32)(w0 + 4) ^ swzf];
            B.u2[0] = *(const uint2*)&bRow[(u32)w0 ^ swzf];
            B.u2[1] = *(const uint2*)&bRow[(u32)(w0 + 4) ^ swzf];
            acc = __builtin_amdgcn_mfma_f32_32x32x16_bf16(A.v, B.v, acc, 0, 0, 0);
        }
        // ---- epilogue: threshold filter + ballot-aggregated queue push ----
        {
            const u32 jg = (u32)(ch * CJ + jloc);
            const float sqj = sSqnj[jloc];
#pragma unroll
            for (int gp = 0; gp < 4; ++gp) {
                const int rb = 8 * gp + 4 * hf;
                float4 s4 = *(const float4*)&sSqni[rb];
                uint4 t4 = *(const uint4*)&thrq[rb];
#pragma unroll
                for (int e = 0; e < 4; ++e) {
                    float se = e == 0 ? s4.x : e == 1 ? s4.y : e == 2 ? s4.z : s4.w;
                    u32 te = e == 0 ? t4.x : e == 1 ? t4.y : e == 2 ? t4.z : t4.w;
                    float dist = fmaf(-2.f, acc[4 * gp + e], se + sqj);
                    u32 kb = (__float_as_uint(dist + 1.0f) & 0xFFFFF000u) | jg;
                    bool pred = kb < te;
                    ull bal = __ballot(pred);
                    u32 half = (u32)(hf ? (bal >> 32) : bal);
                    int tot = __popc(half);
                    int base = 0;
                    if ((lane & 31) == 0 && tot) base = atomicAdd(&qcnt[rb + e], tot);
                    base = __shfl(base, hf << 5, 64);
                    if (pred) sQ[(rb + e) * QST + base + __popc(half & lmask)] = kb;
                }
            }
        }
        __syncthreads();   // (A) pushes visible; all frag reads of cur chunk done
        if (ch + 1 < NCHUNK) stageXj(ch + 1);
        // ---- flush: insert queue entries into per-thread sorted-16 ----
        {
            int cnt = qcnt[si];
            u32 gte = lk[MCT - 1];
            for (int q = st; q < cnt; q += 8) {
                u32 kb = sQ[si * QST + q];
                if (kb < gte) {
                    u32 cur = kb;
#pragma unroll
                    for (int t = 0; t < MCT; ++t) {
                        u32 lo = min(cur, lk[t]);
                        cur = max(cur, lk[t]);
                        lk[t] = lo;
                    }
                    gte = lk[MCT - 1];
                }
            }
            u32 m = gte;
            m = min(m, (u32)__shfl_xor((int)m, 1, 8));
            m = min(m, (u32)__shfl_xor((int)m, 2, 8));
            m = min(m, (u32)__shfl_xor((int)m, 4, 8));
            if (st == 0) { thrq[si] = m; qcnt[si] = 0; }   // same-wave: reads above done
        }
        __syncthreads();   // (B) staging + flush + reset visible
    }

    // ---- dump sorted lists (pool dead) ----
#pragma unroll
    for (int s = 0; s < MCT; ++s) mbk[tid * MBS + s] = lk[s];
    __syncthreads();
    // ---- 8-way merge per row -> top-32 candidate j's ----
    if (st == 0) {
        int p[8];
#pragma unroll
        for (int t = 0; t < 8; ++t) p[t] = 0;
        for (int slot = 0; slot < MROW; ++slot) {
            u32 best = 0xFFFFFFFFu; int bt = 0;
#pragma unroll
            for (int t = 0; t < 8; ++t) {
                int pt = p[t];
                u32 v = (pt < MCT) ? mbk[(si * 8 + t) * MBS + pt] : 0xFFFFFFFFu;
                if (v < best) { best = v; bt = t; }
            }
            p[bt]++;
            sFin[si * MROW + slot] = (int)(best & 0xFFFu);
        }
    }
    __syncthreads();

    // ---- rescore: VALIDATED R11 emulation, 4 cands/thread ----
    ull kk[RESC];
    {
        float xi_[DIM];
        const float* pxi = xb + (size_t)(i0 + si) * DIM;
#pragma unroll
        for (int d4 = 0; d4 < DIM / 4; ++d4) {
            float4 v = *(const float4*)(pxi + 4 * d4);
            xi_[4 * d4 + 0] = v.x; xi_[4 * d4 + 1] = v.y;
            xi_[4 * d4 + 2] = v.z; xi_[4 * d4 + 3] = v.w;
        }
        const float sqi32 = np_sumsq64(xi_);
#pragma unroll
        for (int c = 0; c < RESC; ++c) {
            const int j = sFin[si * MROW + st * RESC + c];
            const float* pxj = xb + (size_t)j * DIM;
            float xj_[DIM];
#pragma unroll
            for (int d4 = 0; d4 < DIM / 4; ++d4) {
                float4 v = *(const float4*)(pxj + 4 * d4);
                xj_[4 * d4 + 0] = v.x; xj_[4 * d4 + 1] = v.y;
                xj_[4 * d4 + 2] = v.z; xj_[4 * d4 + 3] = v.w;
            }
            const float inn   = np_blas_dot64(xi_, xj_);
            const float sqj32 = np_sumsq64(xj_);
            float adj32;
            {
#pragma clang fp contract(off)
                adj32 = (sqi32 - 2.0f * inn) + sqj32;
            }
            u32 bits = __float_as_uint(adj32);
            u32 mu = (bits & 0x80000000u) ? ~bits : (bits | 0x80000000u);
            kk[c] = ((ull)mu << 32) | (u32)j;
        }
    }
    for (int k = 0; k < KNN; ++k) {
        ull m01 = kk[0] < kk[1] ? kk[0] : kk[1];
        ull m23 = kk[2] < kk[3] ? kk[2] : kk[3];
        ull m = m01 < m23 ? m01 : m23;
#pragma unroll
        for (int w = 1; w < 8; w <<= 1) {
            ull o = (ull)__shfl_xor((long long)m, w, 8);
            m = o < m ? o : m;
        }
#pragma unroll
        for (int c = 0; c < RESC; ++c) if (kk[c] == m) kk[c] = ~0ull;
        if (st == 0) sFin[si * MROW + k] = (int)(m & 0xFFFFFFFFull);
    }
    __syncthreads();
    // ---- fused emit ----
    const size_t obase = (size_t)(b * NPTS + i0) * (KNN * 2 * DIM);
    for (int v = tid; v < BI * KNN * 2 * DIM / 4; v += NTH) {
        int v4 = v * 4;
        int ii = v4 / (KNN * 2 * DIM);
        int rr = v4 % (KNN * 2 * DIM);
        int k  = rr / (2 * DIM);
        int d  = rr % (2 * DIM);
        const float* crow = xb + (size_t)(i0 + ii) * DIM;
        float4 o;
        if (d < DIM) {
            o = *(const float4*)(crow + d);
        } else {
            int dd = d - DIM;
            int j  = sFin[ii * MROW + k];
            float4 n4 = *(const float4*)(xb + (size_t)j * DIM + dd);
            float4 c4 = *(const float4*)(crow + dd);
            o.x = n4.x - c4.x;
            o.y = n4.y - c4.y;
            o.z = n4.z - c4.z;
            o.w = n4.w - c4.w;
        }
        *(float4*)(out + obase + v4) = o;
    }
}

extern "C" void kernel_launch(void* const* d_in, const int* in_sizes, int n_in,
                              void* d_out, int out_size, void* d_ws, size_t ws_size,
                              hipStream_t stream) {
    const float* x = (const float*)d_in[0];
    float* out = (float*)d_out;
    dim3 grid(BATCH * (NPTS / BI));
    hipLaunchKernelGGL(edge_knn_kernel, grid, dim3(NTH), 0, stream, x, out);
}

// Round 16
// 381.555 us; speedup vs baseline: 4.4997x; 1.0050x over previous
//
#include <hip/hip_runtime.h>

#define BATCH 8
#define NPTS 4096
#define DIM 64
#define KNN 20
#define BI 32
#define CJ 128
#define MCT 16               // per-thread sorted list
#define MROW 32              // row candidate count after merge
#define NTH 256
#define NCHUNK (NPTS / CJ)   // 32
#define XBP 36               // bf16 row pitch in u32 words
#define QST 132              // queue row stride (u32)
#define MBS 17               // mbk per-thread stride
#define RESC 4               // rescore candidates per thread

typedef unsigned long long ull;
typedef unsigned int u32;
typedef __attribute__((ext_vector_type(8))) __bf16 bf16x8;
typedef __attribute__((ext_vector_type(16))) float f32x16;

union FragU { bf16x8 v; uint2 u2[2]; };

// ===== VALIDATED R11 recipes (bit-exact vs checker) — do not touch =====
__device__ __forceinline__ float np_sumsq64(const float* __restrict__ xv) {
#pragma clang fp contract(off)
    float r[8];
#pragma unroll
    for (int l = 0; l < 8; ++l) { float v = xv[1 + l]; r[l] = v * v; }
#pragma unroll
    for (int t = 1; t < 7; ++t)
#pragma unroll
        for (int l = 0; l < 8; ++l) {
            float v = xv[1 + 8 * t + l];
            float p = v * v;
            r[l] = r[l] + p;
        }
    float res = ((r[0] + r[1]) + (r[2] + r[3])) + ((r[4] + r[5]) + (r[6] + r[7]));
#pragma unroll
    for (int d = 57; d < 64; ++d) { float v = xv[d]; float p = v * v; res = res + p; }
    float a0 = xv[0] * xv[0];
    return a0 + res;
}

__device__ __forceinline__ float np_blas_dot64(const float* __restrict__ xi_,
                                               const float* __restrict__ xj_) {
    float acc = 0.f;
#pragma unroll
    for (int d = 0; d < DIM; ++d) acc = fmaf(xi_[d], xj_[d], acc);
    return acc;
}
// =======================================================================

__global__ __launch_bounds__(NTH, 4) void edge_knn_kernel(const float* __restrict__ x,
                                                          float* __restrict__ out) {
    // LDS: 39936 (pool) + 128 + 512 + 128 + 128 = 40832 B -> 4 blocks/CU
    __shared__ __align__(16) u32 sPool[9984];
    __shared__ __align__(16) float sSqni[BI];
    __shared__ __align__(16) float sSqnj[CJ];
    __shared__ int qcnt[BI];
    __shared__ __align__(16) u32 thrq[BI];

    u32* sXjB = sPool;               // [128][36]
    u32* sXiB = sPool + CJ * XBP;    // [32][36]
    u32* sQ   = sPool + CJ * XBP + BI * XBP;   // [32][132]
    u32* mbk  = sPool;               // overlay after loop: 256*17 = 4352 words
    int* sFin = (int*)(sPool + 4352);// overlay: 32*32 = 1024 words

    const int tid = threadIdx.x;
    const int blk = blockIdx.x;
    const int b   = blk / (NPTS / BI);
    const int i0  = (blk % (NPTS / BI)) * BI;
    const float* xb = x + (size_t)b * NPTS * DIM;

    const int r2 = tid >> 1, h2 = tid & 1;

    auto stageXj = [&](int ch) {
        const float* src = xb + (size_t)(ch * CJ + r2) * DIM + h2 * 32;
        u32* dst = sXjB + r2 * XBP;
        const u32 swz = ((u32)(r2 >> 3) & 3u) << 2;
        float ps = 0.f;
#pragma unroll
        for (int q = 0; q < 4; ++q) {
            float4 va = *(const float4*)(src + q * 8);
            float4 vb = *(const float4*)(src + q * 8 + 4);
            ps = fmaf(va.x, va.x, ps); ps = fmaf(va.y, va.y, ps);
            ps = fmaf(va.z, va.z, ps); ps = fmaf(va.w, va.w, ps);
            ps = fmaf(vb.x, vb.x, ps); ps = fmaf(vb.y, vb.y, ps);
            ps = fmaf(vb.z, vb.z, ps); ps = fmaf(vb.w, vb.w, ps);
            uint4 pk;
            pk.x = (__float_as_uint(va.y) & 0xFFFF0000u) | (__float_as_uint(va.x) >> 16);
            pk.y = (__float_as_uint(va.w) & 0xFFFF0000u) | (__float_as_uint(va.z) >> 16);
            pk.z = (__float_as_uint(vb.y) & 0xFFFF0000u) | (__float_as_uint(vb.x) >> 16);
            pk.w = (__float_as_uint(vb.w) & 0xFFFF0000u) | (__float_as_uint(vb.z) >> 16);
            *(uint4*)&dst[(u32)(h2 * 16 + q * 4) ^ swz] = pk;
        }
        ps += __shfl_xor(ps, 1, 2);
        if (h2 == 0) sSqnj[r2] = ps;
    };

    // ---- prologue ----
    if (tid < 2 * BI) {
        const float* src = xb + (size_t)(i0 + r2) * DIM + h2 * 32;
        u32* dst = sXiB + r2 * XBP;
        const u32 swz = ((u32)(r2 >> 3) & 3u) << 2;
#pragma unroll
        for (int q = 0; q < 4; ++q) {
            float4 va = *(const float4*)(src + q * 8);
            float4 vb = *(const float4*)(src + q * 8 + 4);
            uint4 pk;
            pk.x = (__float_as_uint(va.y) & 0xFFFF0000u) | (__float_as_uint(va.x) >> 16);
            pk.y = (__float_as_uint(va.w) & 0xFFFF0000u) | (__float_as_uint(va.z) >> 16);
            pk.z = (__float_as_uint(vb.y) & 0xFFFF0000u) | (__float_as_uint(vb.x) >> 16);
            pk.w = (__float_as_uint(vb.w) & 0xFFFF0000u) | (__float_as_uint(vb.z) >> 16);
            *(uint4*)&dst[(u32)(h2 * 16 + q * 4) ^ swz] = pk;
        }
    }
    if (tid < BI) {
        const float* p = xb + (size_t)(i0 + tid) * DIM;
        float s = 0.f;
#pragma unroll
        for (int d4 = 0; d4 < 16; ++d4) {
            float4 v = *(const float4*)(p + 4 * d4);
            s = fmaf(v.x, v.x, s); s = fmaf(v.y, v.y, s);
            s = fmaf(v.z, v.z, s); s = fmaf(v.w, v.w, s);
        }
        sSqni[tid] = s;
        qcnt[tid] = 0;
        thrq[tid] = 0xFFFFFFFFu;
    }
    stageXj(0);
    __syncthreads();

    u32 lk[MCT];
#pragma unroll
    for (int s = 0; s < MCT; ++s) lk[s] = 0xFFFFFFFFu;

    const int lane = tid & 63;
    const int wv   = tid >> 6;
    const int nrow = lane & 31;      // = i-column owned by this lane (D[j][i])
    const int hf   = lane >> 5;
    const int si   = tid >> 3;
    const int st   = tid & 7;

    const u32* aRow = sXiB + nrow * XBP;              // Xi row (B operand)
    const u32* bRow = sXjB + (wv * 32 + nrow) * XBP;  // Xj row (A operand)
    const u32 swzf  = ((u32)(nrow >> 3) & 3u) << 2;
    const float sqi_l = sSqni[nrow];                  // lane-constant

    for (int ch = 0; ch < NCHUNK; ++ch) {
        // ---- MFMA: wave's 32(j) x 32(i) tile, K=64: D[j][i], lane owns i ----
        f32x16 acc;
#pragma unroll
        for (int e = 0; e < 16; ++e) acc[e] = 0.f;
#pragma unroll
        for (int ks = 0; ks < 4; ++ks) {
            const int w0 = ks * 8 + 2 * hf;
            FragU XI, XJ;
            XI.u2[0] = *(const uint2*)&aRow[(u32)w0 ^ swzf];
            XI.u2[1] = *(const uint2*)&aRow[(u32)(w0 + 4) ^ swzf];
            XJ.u2[0] = *(const uint2*)&bRow[(u32)w0 ^ swzf];
            XJ.u2[1] = *(const uint2*)&bRow[(u32)(w0 + 4) ^ swzf];
            acc = __builtin_amdgcn_mfma_f32_32x32x16_bf16(XJ.v, XI.v, acc, 0, 0, 0);
        }
        // ---- epilogue: lane-local threshold filter + direct queue push ----
        {
            const u32 thr_i = thrq[nrow];
            const u32 jbase = (u32)(ch * CJ + wv * 32);
#pragma unroll
            for (int gp = 0; gp < 4; ++gp) {
#pragma unroll
                for (int e2 = 0; e2 < 4; ++e2) {
                    const int jr = 8 * gp + e2 + 4 * hf;   // D row = j-local
                    float sqj = sSqnj[wv * 32 + jr];       // broadcast read
                    float dist = fmaf(-2.f, acc[4 * gp + e2], sqi_l + sqj);
                    u32 kb = (__float_as_uint(dist + 1.0f) & 0xFFFFF000u) | (jbase + jr);
                    if (kb < thr_i) {
                        int idx = atomicAdd(&qcnt[nrow], 1);
                        sQ[nrow * QST + idx] = kb;
                    }
                }
            }
        }
        __syncthreads();   // (A) pushes visible; frag reads of cur chunk done
        if (ch + 1 < NCHUNK) stageXj(ch + 1);
        // ---- flush: insert queue entries into per-thread sorted-16 ----
        {
            int cnt = qcnt[si];
            u32 gte = lk[MCT - 1];
            for (int q = st; q < cnt; q += 8) {
                u32 kb = sQ[si * QST + q];
                if (kb < gte) {
                    u32 cur = kb;
#pragma unroll
                    for (int t = 0; t < MCT; ++t) {
                        u32 lo = min(cur, lk[t]);
                        cur = max(cur, lk[t]);
                        lk[t] = lo;
                    }
                    gte = lk[MCT - 1];
                }
            }
            u32 m = gte;
            m = min(m, (u32)__shfl_xor((int)m, 1, 8));
            m = min(m, (u32)__shfl_xor((int)m, 2, 8));
            m = min(m, (u32)__shfl_xor((int)m, 4, 8));
            if (st == 0) { thrq[si] = m; qcnt[si] = 0; }   // same-wave lockstep
        }
        __syncthreads();   // (B) staging + flush + reset visible
    }

    // ---- dump sorted lists (pool dead) ----
#pragma unroll
    for (int s = 0; s < MCT; ++s) mbk[tid * MBS + s] = lk[s];
    __syncthreads();
    // ---- 8-way merge per row -> top-32 candidate j's ----
    if (st == 0) {
        int p[8];
#pragma unroll
        for (int t = 0; t < 8; ++t) p[t] = 0;
        for (int slot = 0; slot < MROW; ++slot) {
            u32 best = 0xFFFFFFFFu; int bt = 0;
#pragma unroll
            for (int t = 0; t < 8; ++t) {
                int pt = p[t];
                u32 v = (pt < MCT) ? mbk[(si * 8 + t) * MBS + pt] : 0xFFFFFFFFu;
                if (v < best) { best = v; bt = t; }
            }
            p[bt]++;
            sFin[si * MROW + slot] = (int)(best & 0xFFFu);
        }
    }
    __syncthreads();

    // ---- rescore: VALIDATED R11 emulation, 4 cands/thread ----
    ull kk[RESC];
    {
        float xi_[DIM];
        const float* pxi = xb + (size_t)(i0 + si) * DIM;
#pragma unroll
        for (int d4 = 0; d4 < DIM / 4; ++d4) {
            float4 v = *(const float4*)(pxi + 4 * d4);
            xi_[4 * d4 + 0] = v.x; xi_[4 * d4 + 1] = v.y;
            xi_[4 * d4 + 2] = v.z; xi_[4 * d4 + 3] = v.w;
        }
        const float sqi32 = np_sumsq64(xi_);
#pragma unroll
        for (int c = 0; c < RESC; ++c) {
            const int j = sFin[si * MROW + st * RESC + c];
            const float* pxj = xb + (size_t)j * DIM;
            float xj_[DIM];
#pragma unroll
            for (int d4 = 0; d4 < DIM / 4; ++d4) {
                float4 v = *(const float4*)(pxj + 4 * d4);
                xj_[4 * d4 + 0] = v.x; xj_[4 * d4 + 1] = v.y;
                xj_[4 * d4 + 2] = v.z; xj_[4 * d4 + 3] = v.w;
            }
            const float inn   = np_blas_dot64(xi_, xj_);
            const float sqj32 = np_sumsq64(xj_);
            float adj32;
            {
#pragma clang fp contract(off)
                adj32 = (sqi32 - 2.0f * inn) + sqj32;
            }
            u32 bits = __float_as_uint(adj32);
            u32 mu = (bits & 0x80000000u) ? ~bits : (bits | 0x80000000u);
            kk[c] = ((ull)mu << 32) | (u32)j;
        }
    }
    for (int k = 0; k < KNN; ++k) {
        ull m01 = kk[0] < kk[1] ? kk[0] : kk[1];
        ull m23 = kk[2] < kk[3] ? kk[2] : kk[3];
        ull m = m01 < m23 ? m01 : m23;
#pragma unroll
        for (int w = 1; w < 8; w <<= 1) {
            ull o = (ull)__shfl_xor((long long)m, w, 8);
            m = o < m ? o : m;
        }
#pragma unroll
        for (int c = 0; c < RESC; ++c) if (kk[c] == m) kk[c] = ~0ull;
        if (st == 0) sFin[si * MROW + k] = (int)(m & 0xFFFFFFFFull);
    }
    __syncthreads();
    // ---- fused emit ----
    const size_t obase = (size_t)(b * NPTS + i0) * (KNN * 2 * DIM);
    for (int v = tid; v < BI * KNN * 2 * DIM / 4; v += NTH) {
        int v4 = v * 4;
        int ii = v4 / (KNN * 2 * DIM);
        int rr = v4 % (KNN * 2 * DIM);
        int k  = rr / (2 * DIM);
        int d  = rr % (2 * DIM);
        const float* crow = xb + (size_t)(i0 + ii) * DIM;
        float4 o;
        if (d < DIM) {
            o = *(const float4*)(crow + d);
        } else {
            int dd = d - DIM;
            int j  = sFin[ii * MROW + k];
            float4 n4 = *(const float4*)(xb + (size_t)j * DIM + dd);
            float4 c4 = *(const float4*)(crow + dd);
            o.x = n4.x - c4.x;
            o.y = n4.y - c4.y;
            o.z = n4.z - c4.z;
            o.w = n4.w - c4.w;
        }
        *(float4*)(out + obase + v4) = o;
    }
}

extern "C" void kernel_launch(void* const* d_in, const int* in_sizes, int n_in,
                              void* d_out, int out_size, void* d_ws, size_t ws_size,
                              hipStream_t stream) {
    const float* x = (const float*)d_in[0];
    float* out = (float*)d_out;
    dim3 grid(BATCH * (NPTS / BI));
    hipLaunchKernelGGL(edge_knn_kernel, grid, dim3(NTH), 0, stream, x, out);
}